// Round 23
// baseline (38.021 us; speedup 1.0000x reference)
//
#include <hip/hip_runtime.h>
#include <hip/hip_fp16.h>

#define B_   8
#define LQ_  128
#define LK_  1024
#define H_   128

// tanh(q+k) = 1 - 2/(EQ*EK + 1), EQ=exp(2q') f32, EK=exp(2k') f16.
// g_ekT4[b][h4][sp] (uint4): uint j = half2( EK[4*h4+j][2*sp], EK[4*h4+j][2*sp+1] )
// g_vh[b][s][v2] half2 along v. g_sc = unnormalized softmax weights.
// Measured absmax 1.95e-3 (R13-R22), threshold 8.3e-3.
__device__ float        g_eq  [B_ * LQ_ * H_];
__device__ uint4        g_ekT4[B_ * (H_ / 4) * (LK_ / 2)];
__device__ unsigned int g_vh  [B_ * LK_ * (H_ / 2)];
__device__ float        g_sc  [B_ * LQ_ * LK_];

#define C2LOG2E 2.8853900817779268f      // 2/ln2

// Merged projection + values-pack. (R17-proven, unchanged)
__global__ __launch_bounds__(256) void proj_conv(const float* __restrict__ q,
                                                 const float* __restrict__ k,
                                                 const float* __restrict__ Wq,
                                                 const float* __restrict__ Wk,
                                                 const float* __restrict__ values) {
    const int bx = blockIdx.x, ch = blockIdx.y;
    const int t = threadIdx.x;
    if (bx >= 288) {                     // ---- values pack ----
        const int idx = ((bx - 288) + (ch << 9)) * 256 + t;
        float4 v = *(const float4*)(values + (size_t)idx * 4);
        __half2 p0 = __floats2half2_rn(v.x, v.y);
        __half2 p1 = __floats2half2_rn(v.z, v.w);
        *(uint2*)(g_vh + (size_t)idx * 2) =
            make_uint2(*(unsigned int*)&p0, *(unsigned int*)&p1);
        return;
    }
    __shared__ float Ws[H_ * 64];
    __shared__ float Xs[32 * H_];
    const bool isq = (bx < 32);
    const float* X; const float* W; int r0;
    if (isq) { X = q; W = Wq; r0 = bx * 32; }
    else     { X = k; W = Wk; r0 = (bx - 32) * 32; }

    #pragma unroll
    for (int u = 0; u < 8; ++u) {
        int p = u * 256 + t;
        int kk = p >> 4, c4 = p & 15;
        *(float4*)(Ws + kk * 64 + c4 * 4) = *(const float4*)(W + kk * H_ + ch * 64 + c4 * 4);
    }
    #pragma unroll
    for (int u = 0; u < 4; ++u) {
        int idx = u * 256 + t;
        int r = idx >> 5, c = idx & 31;
        *(float4*)(Xs + r * H_ + c * 4) = *(const float4*)(X + (size_t)(r0 + r) * H_ + c * 4);
    }
    __syncthreads();

    const int rr = t >> 4;               // [0,16): 2 rows
    const int cc = t & 15;               // [0,16): 4 cols
    float acc[2][4] = {};
    #pragma unroll 4
    for (int kk = 0; kk < H_; ++kk) {
        float4 w4 = *(const float4*)(Ws + kk * 64 + cc * 4);
        float x0 = Xs[(rr * 2) * H_ + kk];
        float x1 = Xs[(rr * 2 + 1) * H_ + kk];
        acc[0][0] = fmaf(x0, w4.x, acc[0][0]); acc[0][1] = fmaf(x0, w4.y, acc[0][1]);
        acc[0][2] = fmaf(x0, w4.z, acc[0][2]); acc[0][3] = fmaf(x0, w4.w, acc[0][3]);
        acc[1][0] = fmaf(x1, w4.x, acc[1][0]); acc[1][1] = fmaf(x1, w4.y, acc[1][1]);
        acc[1][2] = fmaf(x1, w4.z, acc[1][2]); acc[1][3] = fmaf(x1, w4.w, acc[1][3]);
    }
    if (isq) {
        #pragma unroll
        for (int i = 0; i < 2; ++i) {
            float4 o;
            o.x = __builtin_amdgcn_exp2f(acc[i][0] * C2LOG2E);
            o.y = __builtin_amdgcn_exp2f(acc[i][1] * C2LOG2E);
            o.z = __builtin_amdgcn_exp2f(acc[i][2] * C2LOG2E);
            o.w = __builtin_amdgcn_exp2f(acc[i][3] * C2LOG2E);
            *(float4*)(g_eq + (size_t)(r0 + rr * 2 + i) * H_ + ch * 64 + cc * 4) = o;
        }
    } else {
        const int b  = r0 >> 10;
        const int s0 = (r0 & 1023) + rr * 2;
        const int h4 = ch * 16 + cc;
        uint4 pk;
        #pragma unroll
        for (int j = 0; j < 4; ++j) {
            float e0 = __builtin_amdgcn_exp2f(acc[0][j] * C2LOG2E);
            float e1 = __builtin_amdgcn_exp2f(acc[1][j] * C2LOG2E);
            __half2 p = __floats2half2_rn(e0, e1);
            ((unsigned int*)&pk)[j] = *(unsigned int*)&p;
        }
        g_ekT4[((size_t)b * (H_ / 4) + h4) * (LK_ / 2) + (s0 >> 1)] = pk;
    }
}

// Scores -> unnormalized weights, RETIRING grid: (1024 rows, 4 s-quarters)
// x 128 threads. Blocks whose whole s-quarter is masked return immediately
// (~37% avg) and boundary threads early-out -> ~80% active lanes vs the fused
// design's ~50%, and retired blocks free SIMD slots for dynamic backfill.
// No barriers; writes disjoint. Inner loop = R17-proven uint4/f16 form.
__global__ __launch_bounds__(128) void score_kernel(const int* __restrict__ valid_lens,
                                                    const float* __restrict__ w_v) {
    const int row = blockIdx.x;          // b*LQ + l
    const int b = row >> 7;
    int valid = valid_lens[b];
    valid = min(max(valid, 0), LK_);
    const int sbase = (int)blockIdx.y << 8;      // 256 s per block
    if (sbase >= valid) return;                  // block retires instantly
    const int s0 = sbase + 2 * (int)threadIdx.x;
    if (s0 >= valid) return;                     // tail-wave thread retire (no barriers)

    const float* __restrict__ q0 = g_eq + (size_t)row * H_;
    const uint4* __restrict__ ek = g_ekT4 + (size_t)b * (H_ / 4) * (LK_ / 2) + (s0 >> 1);
    float a0 = 0.0f, a1 = 0.0f;
    #pragma unroll 4
    for (int h4 = 0; h4 < H_ / 4; ++h4) {
        uint4 u = ek[(size_t)h4 * (LK_ / 2)];
        #pragma unroll
        for (int j = 0; j < 4; ++j) {
            unsigned int uj = ((const unsigned int*)&u)[j];
            float2 ef = __half22float2(*(const __half2*)&uj);
            const int h = h4 * 4 + j;
            const float qh = q0[h], wh = w_v[h];
            a0 = fmaf(wh, __builtin_amdgcn_rcpf(fmaf(qh, ef.x, 1.0f)), a0);
            a1 = fmaf(wh, __builtin_amdgcn_rcpf(fmaf(qh, ef.y, 1.0f)), a1);
        }
    }
    const float cc = -2.0f * 1.44269504f;
    float e0 = __builtin_amdgcn_exp2f(a0 * cc);
    float e1 = __builtin_amdgcn_exp2f(a1 * cc);
    *(float2*)(g_sc + (size_t)row * LK_ + s0) = make_float2(e0, e1);
}

// Softmax-sum + PV, 2 rows per block (512 x 512). Stage weights from g_sc
// (accumulating masked partial sums), shfl+LDS reduce -> rinv; PV with one
// uint2 f16 values load feeding both rows (R20-proven inner). Barrier-fenced.
__global__ __launch_bounds__(512, 4) void smpv_kernel(const int* __restrict__ valid_lens,
                                                      float* __restrict__ out) {
    __shared__ float sA[LK_], sB[LK_];
    __shared__ float sredA[8], sredB[8];
    __shared__ float rinvs[2];
    __shared__ float part[16][2][H_];    // 16 KB
    const int t = threadIdx.x;
    const int lane = t & 63, wid = t >> 6;
    const int b = blockIdx.x >> 6, l0 = (blockIdx.x & 63) * 2;
    int valid = valid_lens[b];
    valid = min(max(valid, 0), LK_);

    float pA = 0.0f, pB = 0.0f;
    if (valid == 0) {                    // ref: all -1e6 -> uniform
        for (int i = t; i < LK_; i += 512) { sA[i] = 1.0f; sB[i] = 1.0f; }
    } else {
        const float* __restrict__ srcA = g_sc + (size_t)(b * LQ_ + l0) * LK_;
        const float* __restrict__ srcB = srcA + LK_;
        for (int i = t; i < valid; i += 512) {
            float a = srcA[i], bb = srcB[i];
            sA[i] = a; sB[i] = bb;
            pA += a; pB += bb;
        }
    }
    #pragma unroll
    for (int kk = 32; kk; kk >>= 1) {
        pA += __shfl_xor(pA, kk, 64);
        pB += __shfl_xor(pB, kk, 64);
    }
    if (lane == 0) { sredA[wid] = pA; sredB[wid] = pB; }
    __syncthreads();
    if (t < 2) {
        const float* sr = t ? sredB : sredA;
        float s8 = ((sr[0] + sr[1]) + (sr[2] + sr[3]))
                 + ((sr[4] + sr[5]) + (sr[6] + sr[7]));
        rinvs[t] = (valid == 0) ? (1.0f / 1024.0f) : (1.0f / s8);
    }
    __syncthreads();
    const int n = (valid == 0) ? LK_ : valid;

    // PV: one uint2 values load feeds both rows; 16-way s-split.
    const int c = t >> 5;                // s-chunk [0,16)
    const int v4 = t & 31;               // 4-v group
    const uint2* vb = (const uint2*)g_vh + (size_t)b * LK_ * (H_ / 4) + v4;
    float ax0 = 0.0f, ay0 = 0.0f, az0 = 0.0f, aw0 = 0.0f;
    float ax1 = 0.0f, ay1 = 0.0f, az1 = 0.0f, aw1 = 0.0f;
    #pragma unroll 4
    for (int s = c; s < n; s += 16) {
        uint2 u = vb[(size_t)s * (H_ / 4)];
        float2 v01 = __half22float2(*(const __half2*)&u.x);
        float2 v23 = __half22float2(*(const __half2*)&u.y);
        float w0 = sA[s], w1 = sB[s];
        ax0 = fmaf(w0, v01.x, ax0); ay0 = fmaf(w0, v01.y, ay0);
        az0 = fmaf(w0, v23.x, az0); aw0 = fmaf(w0, v23.y, aw0);
        ax1 = fmaf(w1, v01.x, ax1); ay1 = fmaf(w1, v01.y, ay1);
        az1 = fmaf(w1, v23.x, az1); aw1 = fmaf(w1, v23.y, aw1);
    }
    *(float4*)(&part[c][0][4 * v4]) = make_float4(ax0, ay0, az0, aw0);
    *(float4*)(&part[c][1][4 * v4]) = make_float4(ax1, ay1, az1, aw1);
    __syncthreads();
    if (t < 256) {
        const int rr = t >> 7, v = t & 127;
        float o = 0.0f;
        #pragma unroll
        for (int cc2 = 0; cc2 < 16; ++cc2) o += part[cc2][rr][v];
        out[(size_t)(b * LQ_ + l0 + rr) * H_ + v] = o * rinvs[rr];
    }
}

extern "C" void kernel_launch(void* const* d_in, const int* in_sizes, int n_in,
                              void* d_out, int out_size, void* d_ws, size_t ws_size,
                              hipStream_t stream) {
    const float* queries    = (const float*)d_in[0];
    const float* keys       = (const float*)d_in[1];
    const float* values     = (const float*)d_in[2];
    const int*   valid_lens = (const int*)d_in[3];
    const float* W_q        = (const float*)d_in[4];
    const float* W_k        = (const float*)d_in[5];
    const float* w_v        = (const float*)d_in[6];
    float* out = (float*)d_out;
    (void)d_ws; (void)ws_size; (void)in_sizes; (void)n_in; (void)out_size;

    proj_conv   <<<dim3(800, 2), 256, 0, stream>>>(queries, keys, W_q, W_k, values);
    score_kernel<<<dim3(B_ * LQ_, 4), 128, 0, stream>>>(valid_lens, w_v);
    smpv_kernel <<<512, 512, 0, stream>>>(valid_lens, out);
}